// Round 1
// baseline (120.887 us; speedup 1.0000x reference)
//
#include <hip/hip_runtime.h>

#define T_TOTAL 262144
#define NMIX 64
#define NDIM 16

// ws layout (as floats):
//   [0 .. 1023]     g[m][d]  = -0.5*log2e*prec
//   [1024 .. 2047]  h[m][d]  =  log2e*prec*mu
//   [2048 .. 2111]  A2[m]    = log2(C_m) - 0.5*log2e*sum(prec*mu^2)
//   [2112 .. 2113]  double accumulator for sum of log2(like)
#define WS_G 0
#define WS_H 1024
#define WS_A 2048
#define WS_ACC 2112   // float offset; 2112*4 = 8448 bytes, 8B aligned

__global__ void gmm_prep(const float* __restrict__ wghts,
                         const float* __restrict__ means,
                         const float* __restrict__ dcovs,
                         float* __restrict__ ws) {
    int m = threadIdx.x;
    if (m == 0) {
        *reinterpret_cast<double*>(ws + WS_ACC) = 0.0;  // zero the atomic accumulator
    }
    if (m >= NMIX) return;
    const float LOG2E = 1.4426950408889634f;
    const float LOG2_2PI = 2.6514961294723187f;  // log2(6.283185307)
    float sumlog = 0.0f, qsum = 0.0f;
    for (int d = 0; d < NDIM; ++d) {
        float dc = dcovs[m * NDIM + d];
        float mu = means[m * NDIM + d];
        float pr = 1.0f / dc;
        ws[WS_G + m * NDIM + d] = -0.5f * LOG2E * pr;
        ws[WS_H + m * NDIM + d] = LOG2E * pr * mu;
        sumlog += __builtin_amdgcn_logf(dc);     // log2(dc)
        qsum += pr * mu * mu;
    }
    // log2(C_m) = log2(w_m) - (D/2)*log2(2pi) - 0.5*sum(log2 dcov)
    float log2C = __builtin_amdgcn_logf(wghts[m]) - 8.0f * LOG2_2PI - 0.5f * sumlog;
    ws[WS_A + m] = log2C - 0.5f * LOG2E * qsum;
}

__global__ __launch_bounds__(256) void gmm_main(const float* __restrict__ data,
                                                const float* __restrict__ means,
                                                const float* __restrict__ ws,
                                                float* __restrict__ out,
                                                double* __restrict__ acc) {
    __shared__ float tile[256 * 17];
    __shared__ float wsum[4];

    const int tid = threadIdx.x;
    const size_t t = (size_t)blockIdx.x * 256 + tid;

    // ---- load this thread's point into registers (float4 x4) ----
    float x[16], xs[16];
    {
        const float4* xp = reinterpret_cast<const float4*>(data + t * NDIM);
        float4 a = xp[0], b = xp[1], c = xp[2], d4 = xp[3];
        x[0]=a.x;  x[1]=a.y;  x[2]=a.z;  x[3]=a.w;
        x[4]=b.x;  x[5]=b.y;  x[6]=b.z;  x[7]=b.w;
        x[8]=c.x;  x[9]=c.y;  x[10]=c.z; x[11]=c.w;
        x[12]=d4.x;x[13]=d4.y;x[14]=d4.z;x[15]=d4.w;
    }
#pragma unroll
    for (int d = 0; d < 16; ++d) xs[d] = x[d] * x[d];

    const float* __restrict__ g  = ws + WS_G;
    const float* __restrict__ h  = ws + WS_H;
    const float* __restrict__ A2 = ws + WS_A;

    float like = 0.0f;
    float em[16];
#pragma unroll
    for (int d = 0; d < 16; ++d) em[d] = 0.0f;

    for (int m = 0; m < NMIX; ++m) {
        // s = A2[m] + sum_d g*x^2 + h*x   (4 accumulators to break latency chain)
        float s0 = A2[m], s1 = 0.0f, s2 = 0.0f, s3 = 0.0f;
        const int mb = m * NDIM;
#pragma unroll
        for (int d = 0; d < 16; d += 4) {
            s0 = fmaf(g[mb + d + 0], xs[d + 0], s0);
            s1 = fmaf(g[mb + d + 1], xs[d + 1], s1);
            s2 = fmaf(g[mb + d + 2], xs[d + 2], s2);
            s3 = fmaf(g[mb + d + 3], xs[d + 3], s3);
            s0 = fmaf(h[mb + d + 0], x[d + 0], s0);
            s1 = fmaf(h[mb + d + 1], x[d + 1], s1);
            s2 = fmaf(h[mb + d + 2], x[d + 2], s2);
            s3 = fmaf(h[mb + d + 3], x[d + 3], s3);
        }
        float p = __builtin_amdgcn_exp2f((s0 + s1) + (s2 + s3));  // = prob (constants folded)
        like += p;
#pragma unroll
        for (int d = 0; d < 16; ++d) {
            em[d] = fmaf(p, means[mb + d], em[d]);
        }
    }

    // guard against total underflow (keeps NaN out; ref also underflows in fp32)
    float like_c = fmaxf(like, 1e-35f);

    // ---- block reduction of log2(like) ----
    float ll = __builtin_amdgcn_logf(like_c);  // log2
#pragma unroll
    for (int off = 32; off > 0; off >>= 1) ll += __shfl_down(ll, off, 64);
    const int wave = tid >> 6, lane = tid & 63;
    if (lane == 0) wsum[wave] = ll;
    __syncthreads();
    if (tid == 0) {
        double bl = (double)(wsum[0] + wsum[1]) + (double)(wsum[2] + wsum[3]);
        atomicAdd(acc, bl);
    }

    // ---- e_means through LDS (padded stride 17) then coalesced store ----
    float inv = 1.0f / like_c;
#pragma unroll
    for (int d = 0; d < 16; ++d) tile[tid * 17 + d] = em[d] * inv;
    __syncthreads();

    const size_t base = (size_t)blockIdx.x * 4096;
#pragma unroll
    for (int k = 0; k < 16; ++k) {
        int j = tid + k * 256;
        int r = j >> 4, d = j & 15;
        out[1 + base + j] = tile[r * 17 + d];
    }
}

__global__ void gmm_fin(const double* __restrict__ acc, float* __restrict__ out) {
    const double LN2 = 0.6931471805599453;
    out[0] = (float)((*acc) * LN2 / (double)T_TOTAL);
}

extern "C" void kernel_launch(void* const* d_in, const int* in_sizes, int n_in,
                              void* d_out, int out_size, void* d_ws, size_t ws_size,
                              hipStream_t stream) {
    const float* data  = (const float*)d_in[0];
    const float* wghts = (const float*)d_in[1];
    const float* means = (const float*)d_in[2];
    const float* dcovs = (const float*)d_in[3];
    float* out = (float*)d_out;
    float* ws  = (float*)d_ws;
    double* acc = reinterpret_cast<double*>(ws + WS_ACC);

    gmm_prep<<<1, 64, 0, stream>>>(wghts, means, dcovs, ws);
    gmm_main<<<T_TOTAL / 256, 256, 0, stream>>>(data, means, ws, out, acc);
    gmm_fin<<<1, 1, 0, stream>>>(acc, out);
}

// Round 2
// 109.918 us; speedup vs baseline: 1.0998x; 1.0998x over previous
//
#include <hip/hip_runtime.h>

#define T_TOTAL 262144
#define NMIX 64
#define NDIM 16

// ws layout (floats):
//   rec[m][64], m in [0,64):  [0:16)=g  [16:32)=h  [32:48)=mu  [48]=A2  [49:64) pad
//     g  = -0.5*log2e*prec
//     h  =  log2e*prec*mu
//     A2 =  log2(C_m) - 0.5*log2e*sum(prec*mu^2)
//   [4096..4097] double accumulator for sum of log2(like)
#define WS_REC 0
#define WS_ACC 4096   // float offset; 4096*4 = 16384 bytes, 8B aligned

typedef float f2 __attribute__((ext_vector_type(2)));

__global__ void gmm_prep(const float* __restrict__ wghts,
                         const float* __restrict__ means,
                         const float* __restrict__ dcovs,
                         float* __restrict__ ws) {
    int m = threadIdx.x;
    if (m == 0) {
        *reinterpret_cast<double*>(ws + WS_ACC) = 0.0;  // zero the atomic accumulator
    }
    if (m >= NMIX) return;
    const float LOG2E = 1.4426950408889634f;
    const float LOG2_2PI = 2.6514961294723187f;  // log2(2*pi)
    float* rec = ws + WS_REC + m * 64;
    float sumlog = 0.0f, qsum = 0.0f;
    for (int d = 0; d < NDIM; ++d) {
        float dc = dcovs[m * NDIM + d];
        float mu = means[m * NDIM + d];
        float pr = 1.0f / dc;
        rec[d]      = -0.5f * LOG2E * pr;
        rec[16 + d] = LOG2E * pr * mu;
        rec[32 + d] = mu;
        sumlog += __builtin_amdgcn_logf(dc);     // log2
        qsum   += pr * mu * mu;
    }
    float log2C = __builtin_amdgcn_logf(wghts[m]) - 8.0f * LOG2_2PI - 0.5f * sumlog;
    rec[48] = log2C - 0.5f * LOG2E * qsum;
}

__global__ __launch_bounds__(256) void gmm_main(const float* __restrict__ data,
                                                const float* __restrict__ ws,
                                                float* __restrict__ out,
                                                double* __restrict__ acc) {
    __shared__ float tile[256 * 18];
    __shared__ float wsum[4];

    const int tid = threadIdx.x;
    const size_t t = (size_t)blockIdx.x * 256 + tid;

    // ---- this thread's point, as float2 pairs (for v_pk_fma_f32) ----
    f2 x2[8], xs2[8], em2[8];
    {
        const float4* xp = reinterpret_cast<const float4*>(data + t * NDIM);
        float4 a = xp[0], b = xp[1], c = xp[2], d4 = xp[3];
        x2[0] = f2{a.x, a.y};   x2[1] = f2{a.z, a.w};
        x2[2] = f2{b.x, b.y};   x2[3] = f2{b.z, b.w};
        x2[4] = f2{c.x, c.y};   x2[5] = f2{c.z, c.w};
        x2[6] = f2{d4.x, d4.y}; x2[7] = f2{d4.z, d4.w};
    }
#pragma unroll
    for (int j = 0; j < 8; ++j) { xs2[j] = x2[j] * x2[j]; em2[j] = f2{0.0f, 0.0f}; }

    float like = 0.0f;

#pragma unroll 2
    for (int m = 0; m < NMIX; ++m) {
        const float* __restrict__ rec = ws + WS_REC + m * 64;  // wave-uniform -> s_load
        // s = A2 + sum_d g*x^2 + h*x, packed f32, 4 independent f2 accumulators
        f2 sa = f2{rec[48], 0.0f};
        f2 sb = f2{0.0f, 0.0f};
        f2 sc = f2{0.0f, 0.0f};
        f2 sd = f2{0.0f, 0.0f};
#pragma unroll
        for (int j = 0; j < 8; j += 4) {
            sa += f2{rec[2*j + 0], rec[2*j + 1]} * xs2[j + 0];
            sb += f2{rec[2*j + 2], rec[2*j + 3]} * xs2[j + 1];
            sc += f2{rec[2*j + 4], rec[2*j + 5]} * xs2[j + 2];
            sd += f2{rec[2*j + 6], rec[2*j + 7]} * xs2[j + 3];
            sa += f2{rec[16 + 2*j + 0], rec[16 + 2*j + 1]} * x2[j + 0];
            sb += f2{rec[16 + 2*j + 2], rec[16 + 2*j + 3]} * x2[j + 1];
            sc += f2{rec[16 + 2*j + 4], rec[16 + 2*j + 5]} * x2[j + 2];
            sd += f2{rec[16 + 2*j + 6], rec[16 + 2*j + 7]} * x2[j + 3];
        }
        f2 sv = (sa + sb) + (sc + sd);
        float p = __builtin_amdgcn_exp2f(sv.x + sv.y);
        like += p;
        f2 p2 = f2{p, p};
#pragma unroll
        for (int j = 0; j < 8; ++j) {
            em2[j] += p2 * f2{rec[32 + 2*j], rec[32 + 2*j + 1]};
        }
    }

    float like_c = fmaxf(like, 1e-35f);

    // ---- block reduction of log2(like) ----
    float ll = __builtin_amdgcn_logf(like_c);  // log2
#pragma unroll
    for (int off = 32; off > 0; off >>= 1) ll += __shfl_down(ll, off, 64);
    const int wave = tid >> 6, lane = tid & 63;
    if (lane == 0) wsum[wave] = ll;
    __syncthreads();
    if (tid == 0) {
        double bl = (double)(wsum[0] + wsum[1]) + (double)(wsum[2] + wsum[3]);
        atomicAdd(acc, bl);
    }

    // ---- e_means through LDS (stride 18: b64-aligned, 2-way alias = free) ----
    float inv = 1.0f / like_c;
#pragma unroll
    for (int j = 0; j < 8; ++j) {
        f2 v = em2[j] * f2{inv, inv};
        *reinterpret_cast<f2*>(&tile[tid * 18 + 2 * j]) = v;  // ds_write_b64
    }
    __syncthreads();

    const size_t base = (size_t)blockIdx.x * 4096;
#pragma unroll
    for (int k = 0; k < 16; ++k) {
        int j = tid + k * 256;
        int r = j >> 4, d = j & 15;
        out[1 + base + j] = tile[r * 18 + d];
    }
}

__global__ void gmm_fin(const double* __restrict__ acc, float* __restrict__ out) {
    const double LN2 = 0.6931471805599453;
    out[0] = (float)((*acc) * LN2 / (double)T_TOTAL);
}

extern "C" void kernel_launch(void* const* d_in, const int* in_sizes, int n_in,
                              void* d_out, int out_size, void* d_ws, size_t ws_size,
                              hipStream_t stream) {
    const float* data  = (const float*)d_in[0];
    const float* wghts = (const float*)d_in[1];
    const float* means = (const float*)d_in[2];
    const float* dcovs = (const float*)d_in[3];
    float* out = (float*)d_out;
    float* ws  = (float*)d_ws;
    double* acc = reinterpret_cast<double*>(ws + WS_ACC);

    gmm_prep<<<1, 64, 0, stream>>>(wghts, means, dcovs, ws);
    gmm_main<<<T_TOTAL / 256, 256, 0, stream>>>(data, ws, out, acc);
    gmm_fin<<<1, 1, 0, stream>>>(acc, out);
}

// Round 3
// 109.403 us; speedup vs baseline: 1.1050x; 1.0047x over previous
//
#include <hip/hip_runtime.h>

#define T_TOTAL 262144
#define NMIX 64
#define NDIM 16

typedef short bf16x8 __attribute__((ext_vector_type(8)));
typedef unsigned short u16x8 __attribute__((ext_vector_type(8)));
typedef float f32x4 __attribute__((ext_vector_type(4)));

// ws global layout (bytes):
//   G_WH:  64 m x 32 k bf16 hi  (k 0..15 = g coeffs of x^2, k 16..31 = h coeffs of x)
//   G_WL:  same, lo part
//   G_MUT: 16 d x 64 m bf16 (transposed means)
//   G_A2:  64 f32  A2[m] = log2(C_m) - 0.5*log2e*sum(prec*mu^2)
//   G_ACC: double accumulator for sum of log2(like)
#define G_WH   0
#define G_WL   4096
#define G_MUT  8192
#define G_A2   10240
#define G_ACC  10496

__device__ __forceinline__ unsigned short f2bf(float f) {
    union { float f; unsigned u; } v; v.f = f;
    unsigned r = v.u + 0x7fff + ((v.u >> 16) & 1);   // RNE
    return (unsigned short)(r >> 16);
}
__device__ __forceinline__ float bf2f(unsigned short s) {
    union { unsigned u; float f; } v; v.u = ((unsigned)s) << 16;
    return v.f;
}

__global__ void gmm_prep(const float* __restrict__ wghts,
                         const float* __restrict__ means,
                         const float* __restrict__ dcovs,
                         char* __restrict__ ws) {
    int m = threadIdx.x;
    if (m == 0) *(double*)(ws + G_ACC) = 0.0;
    if (m >= NMIX) return;
    unsigned short* wh  = (unsigned short*)(ws + G_WH);
    unsigned short* wl  = (unsigned short*)(ws + G_WL);
    unsigned short* mut = (unsigned short*)(ws + G_MUT);
    float* a2 = (float*)(ws + G_A2);
    const float LOG2E = 1.4426950408889634f;
    const float LOG2_2PI = 2.6514961294723187f;  // log2(6.283185307)
    float sumlog = 0.0f, qsum = 0.0f;
    for (int d = 0; d < NDIM; ++d) {
        float dc = dcovs[m * 16 + d], mu = means[m * 16 + d];
        float pr = 1.0f / dc;
        float g = -0.5f * LOG2E * pr;     // coeff of x^2
        float h = LOG2E * pr * mu;        // coeff of x
        unsigned short gh = f2bf(g);
        wh[m * 32 + d] = gh;           wl[m * 32 + d] = f2bf(g - bf2f(gh));
        unsigned short hh = f2bf(h);
        wh[m * 32 + 16 + d] = hh;      wl[m * 32 + 16 + d] = f2bf(h - bf2f(hh));
        mut[d * 64 + m] = f2bf(mu);
        sumlog += __builtin_amdgcn_logf(dc);   // log2
        qsum   += pr * mu * mu;
    }
    float log2C = __builtin_amdgcn_logf(wghts[m]) - 8.0f * LOG2_2PI - 0.5f * sumlog;
    a2[m] = log2C - 0.5f * LOG2E * qsum;
}

// LDS layout (bytes):
//   L_WH  0      64 rows x 80 B (32 bf16 + pad)         5120
//   L_WL  5120                                           5120
//   L_MUT 10240  16 rows x 144 B (64 bf16 + pad)         2304
//   L_A2  12544  64 f32                                   256
//   L_RED 12800  4 f32 loglike partials                    64
//   L_F   12864  4 waves x (Fh 32x80 | Fl 32x80) = 5120  20480
//   L_P   33344  4 waves x 16 rows x 144 B               9216
//   total 42560
#define L_WH   0
#define L_WL   5120
#define L_MUT  10240
#define L_A2   12544
#define L_RED  12800
#define L_F    12864
#define L_P    33344

__global__ __launch_bounds__(256, 3) void gmm_main(const float* __restrict__ data,
                                                   const char* __restrict__ wsg,
                                                   float* __restrict__ out,
                                                   double* __restrict__ acc) {
    __shared__ __align__(16) char lds[42560];
    const int tid  = threadIdx.x;
    const int w    = tid >> 6;        // wave id
    const int lane = tid & 63;
    const int gi   = lane & 15;       // fragment row/col index
    const int gq   = lane >> 4;       // fragment quad
    const size_t tblk = (size_t)blockIdx.x * 128;

    // ---- stage W hi/lo (64x32 bf16 each) ----
    {
        int row = tid >> 2, seg = tid & 3;
        *(uint4*)(lds + L_WH + row * 80 + seg * 16) =
            *(const uint4*)(wsg + G_WH + row * 64 + seg * 16);
        *(uint4*)(lds + L_WL + row * 80 + seg * 16) =
            *(const uint4*)(wsg + G_WL + row * 64 + seg * 16);
    }
    if (tid < 128) {
        int row = tid >> 3, seg = tid & 7;
        *(uint4*)(lds + L_MUT + row * 144 + seg * 16) =
            *(const uint4*)(wsg + G_MUT + row * 128 + seg * 16);
    }
    if (tid < 64) ((float*)(lds + L_A2))[tid] = ((const float*)(wsg + G_A2))[tid];

    // ---- stage F: features [x^2(16), x(16)] hi/lo bf16, 128 points/block ----
    {
        int row = tid >> 1, half = tid & 1;   // local point 0..127, dim-half
        int fw = row >> 5, lr = row & 31;     // owning wave region, local row
        const float4* xp = (const float4*)(data + (tblk + row) * 16 + half * 8);
        float4 xa = xp[0], xb = xp[1];
        float xv[8] = {xa.x, xa.y, xa.z, xa.w, xb.x, xb.y, xb.z, xb.w};
        u16x8 vh2, vl2, vhx, vlx;
#pragma unroll
        for (int d = 0; d < 8; ++d) {
            float q = xv[d] * xv[d];
            unsigned short qh = f2bf(q);
            vh2[d] = qh;               vl2[d] = f2bf(q - bf2f(qh));
            unsigned short xh = f2bf(xv[d]);
            vhx[d] = xh;               vlx[d] = f2bf(xv[d] - bf2f(xh));
        }
        char* fb = lds + L_F + fw * 5120 + lr * 80;
        *(u16x8*)(fb + half * 16)        = vh2;   // k = half*8+d   (x^2 terms)
        *(u16x8*)(fb + 32 + half * 16)   = vhx;   // k = 16+half*8+d (x terms)
        char* fl = fb + 2560;
        *(u16x8*)(fl + half * 16)        = vl2;
        *(u16x8*)(fl + 32 + half * 16)   = vlx;
    }
    __syncthreads();

    // ---- preload B fragments (wave-invariant) ----
    bf16x8 bh[4], bl[4];
    float a2v[4];
#pragma unroll
    for (int c = 0; c < 4; ++c) {
        bh[c] = *(const bf16x8*)(lds + L_WH + (c * 16 + gi) * 80 + gq * 16);
        bl[c] = *(const bf16x8*)(lds + L_WL + (c * 16 + gi) * 80 + gq * 16);
        a2v[c] = ((const float*)(lds + L_A2))[c * 16 + gi];
    }
    bf16x8 mf0 = *(const bf16x8*)(lds + L_MUT + gi * 144 + gq * 16);
    bf16x8 mf1 = *(const bf16x8*)(lds + L_MUT + gi * 144 + 64 + gq * 16);

    const char* fbase = lds + L_F + w * 5120;
    char* pbase = lds + L_P + w * 2304;
    float ll_acc = 0.0f;

#pragma unroll
    for (int rt = 0; rt < 2; ++rt) {
        // A fragments: rows rt*16+gi of this wave's F tile
        bf16x8 ah = *(const bf16x8*)(fbase + (rt * 16 + gi) * 80 + gq * 16);
        bf16x8 al = *(const bf16x8*)(fbase + 2560 + (rt * 16 + gi) * 80 + gq * 16);

        // S = fh*wh + fh*wl + fl*wh  (hi/lo split), 4 column tiles of 16 m
        f32x4 pacc[4];
#pragma unroll
        for (int c = 0; c < 4; ++c) {
            f32x4 a = {0.0f, 0.0f, 0.0f, 0.0f};
            a = __builtin_amdgcn_mfma_f32_16x16x32_bf16(al, bh[c], a, 0, 0, 0);
            a = __builtin_amdgcn_mfma_f32_16x16x32_bf16(ah, bl[c], a, 0, 0, 0);
            a = __builtin_amdgcn_mfma_f32_16x16x32_bf16(ah, bh[c], a, 0, 0, 0);
            pacc[c] = a;
        }

        // exp2 + row sums (C layout: row = gq*4+reg, col = c*16+gi)
        float p[4][4], prow[4], inv[4];
#pragma unroll
        for (int reg = 0; reg < 4; ++reg) {
#pragma unroll
            for (int c = 0; c < 4; ++c)
                p[c][reg] = __builtin_amdgcn_exp2f(pacc[c][reg] + a2v[c]);
            prow[reg] = (p[0][reg] + p[1][reg]) + (p[2][reg] + p[3][reg]);
        }
#pragma unroll
        for (int reg = 0; reg < 4; ++reg) {
            float v = prow[reg];
            v += __shfl_xor(v, 1);  v += __shfl_xor(v, 2);
            v += __shfl_xor(v, 4);  v += __shfl_xor(v, 8);
            v = fmaxf(v, 1e-35f);
            ll_acc += __builtin_amdgcn_logf(v);       // log2
            inv[reg] = __builtin_amdgcn_rcpf(v);
        }

        // P -> bf16, C layout -> A layout via wave-local LDS tile
#pragma unroll
        for (int c = 0; c < 4; ++c)
#pragma unroll
            for (int reg = 0; reg < 4; ++reg)
                *(unsigned short*)(pbase + (gq * 4 + reg) * 144 + (c * 16 + gi) * 2) =
                    f2bf(p[c][reg]);

        // E = P @ MU  (K=64, 2 k-steps)
        bf16x8 ap0 = *(const bf16x8*)(pbase + gi * 144 + gq * 16);
        bf16x8 ap1 = *(const bf16x8*)(pbase + gi * 144 + 64 + gq * 16);
        f32x4 e = {0.0f, 0.0f, 0.0f, 0.0f};
        e = __builtin_amdgcn_mfma_f32_16x16x32_bf16(ap0, mf0, e, 0, 0, 0);
        e = __builtin_amdgcn_mfma_f32_16x16x32_bf16(ap1, mf1, e, 0, 0, 0);

        // store normalized e_means (C layout: row = gq*4+reg -> t, col = gi -> d)
        size_t trow = tblk + (size_t)w * 32 + rt * 16 + gq * 4;
#pragma unroll
        for (int reg = 0; reg < 4; ++reg)
            out[1 + (trow + reg) * 16 + gi] = e[reg] * inv[reg];
    }

    // ---- loglike: reduce across quads (rows are per (gq,reg); gi lanes duplicate) ----
    ll_acc += __shfl_xor(ll_acc, 16);
    ll_acc += __shfl_xor(ll_acc, 32);
    if (lane == 0) ((float*)(lds + L_RED))[w] = ll_acc;
    __syncthreads();
    if (tid == 0) {
        float* r = (float*)(lds + L_RED);
        atomicAdd(acc, (double)((r[0] + r[1]) + (r[2] + r[3])));
    }
}

__global__ void gmm_fin(const double* __restrict__ acc, float* __restrict__ out) {
    const double LN2 = 0.6931471805599453;
    out[0] = (float)((*acc) * LN2 / (double)T_TOTAL);
}

extern "C" void kernel_launch(void* const* d_in, const int* in_sizes, int n_in,
                              void* d_out, int out_size, void* d_ws, size_t ws_size,
                              hipStream_t stream) {
    const float* data  = (const float*)d_in[0];
    const float* wghts = (const float*)d_in[1];
    const float* means = (const float*)d_in[2];
    const float* dcovs = (const float*)d_in[3];
    float* out = (float*)d_out;
    char* ws   = (char*)d_ws;
    double* acc = (double*)(ws + G_ACC);

    gmm_prep<<<1, 64, 0, stream>>>(wghts, means, dcovs, ws);
    gmm_main<<<T_TOTAL / 128, 256, 0, stream>>>(data, ws, out, acc);
    gmm_fin<<<1, 1, 0, stream>>>(acc, out);
}

// Round 4
// 88.036 us; speedup vs baseline: 1.3732x; 1.2427x over previous
//
#include <hip/hip_runtime.h>

#define T_TOTAL 262144
#define NMIX 64
#define NDIM 16

typedef short bf16x8 __attribute__((ext_vector_type(8)));
typedef unsigned short u16x8 __attribute__((ext_vector_type(8)));
typedef float f32x4 __attribute__((ext_vector_type(4)));

__device__ __forceinline__ unsigned short f2bf(float f) {
    union { float f; unsigned u; } v; v.f = f;
    unsigned r = v.u + 0x7fff + ((v.u >> 16) & 1);   // RNE
    return (unsigned short)(r >> 16);
}
__device__ __forceinline__ float bf2f(unsigned short s) {
    union { unsigned u; float f; } v; v.u = ((unsigned)s) << 16;
    return v.f;
}

// LDS layout (bytes):
//   L_WH  0      64 rows x 80 B (32 bf16 + pad)         5120
//   L_WL  5120                                           5120
//   L_MUT 10240  16 rows x 144 B (64 bf16 + pad)         2304
//   L_A2  12544  64 f32                                   256
//   L_RED 12800  4 f32 loglike partials                    64
//   L_F   12864  4 waves x (Fh 32x80 | Fl 32x80)        20480
//   L_P   33344  4 waves x 16 rows x 144 B               9216
//   total 42560
#define L_WH   0
#define L_WL   5120
#define L_MUT  10240
#define L_A2   12544
#define L_RED  12800
#define L_F    12864
#define L_P    33344

__global__ __launch_bounds__(256, 3) void gmm_main(const float* __restrict__ data,
                                                   const float* __restrict__ wghts,
                                                   const float* __restrict__ means,
                                                   const float* __restrict__ dcovs,
                                                   float* __restrict__ out,
                                                   float* __restrict__ part) {
    __shared__ __align__(16) char lds[42560];
    const int tid  = threadIdx.x;
    const int w    = tid >> 6;        // wave id
    const int lane = tid & 63;
    const int gi   = lane & 15;       // fragment row/col index
    const int gq   = lane >> 4;       // fragment quad
    const size_t tblk = (size_t)blockIdx.x * 128;

    // ---- phase A: issue this thread's data loads (overlap with W prep) ----
    const int row = tid >> 1, half = tid & 1;     // local point 0..127, dim-half
    const float4* xp = (const float4*)(data + (tblk + row) * 16 + half * 8);
    float4 xa = xp[0], xb = xp[1];

    // ---- phase B: W/MU/A2 prep by wave 0 (m = tid) from raw params ----
    if (tid < 64) {
        const int m = tid;
        const float LOG2E = 1.4426950408889634f;
        const float LOG2_2PI = 2.6514961294723187f;  // log2(6.283185307)
        float dc[16], mu[16];
        {
            const float4* dp = (const float4*)(dcovs + m * 16);
            const float4* mp = (const float4*)(means + m * 16);
#pragma unroll
            for (int q = 0; q < 4; ++q) {
                float4 d4 = dp[q], m4 = mp[q];
                dc[q*4+0]=d4.x; dc[q*4+1]=d4.y; dc[q*4+2]=d4.z; dc[q*4+3]=d4.w;
                mu[q*4+0]=m4.x; mu[q*4+1]=m4.y; mu[q*4+2]=m4.z; mu[q*4+3]=m4.w;
            }
        }
        u16x8 ghv[2], glv[2], hhv[2], hlv[2];
        float sumlog = 0.0f, qsum = 0.0f;
        unsigned short* mut = (unsigned short*)(lds + L_MUT);
#pragma unroll
        for (int d = 0; d < 16; ++d) {
            float pr = 1.0f / dc[d];
            float g = -0.5f * LOG2E * pr;     // coeff of x^2
            float h = LOG2E * pr * mu[d];     // coeff of x
            unsigned short gh = f2bf(g), hh = f2bf(h);
            ghv[d >> 3][d & 7] = gh;   glv[d >> 3][d & 7] = f2bf(g - bf2f(gh));
            hhv[d >> 3][d & 7] = hh;   hlv[d >> 3][d & 7] = f2bf(h - bf2f(hh));
            mut[d * 72 + m] = f2bf(mu[d]);
            sumlog += __builtin_amdgcn_logf(dc[d]);   // log2
            qsum   += pr * mu[d] * mu[d];
        }
        char* wrh = lds + L_WH + m * 80;
        char* wrl = lds + L_WL + m * 80;
        *(u16x8*)(wrh)      = ghv[0];  *(u16x8*)(wrh + 16) = ghv[1];
        *(u16x8*)(wrh + 32) = hhv[0];  *(u16x8*)(wrh + 48) = hhv[1];
        *(u16x8*)(wrl)      = glv[0];  *(u16x8*)(wrl + 16) = glv[1];
        *(u16x8*)(wrl + 32) = hlv[0];  *(u16x8*)(wrl + 48) = hlv[1];
        float log2C = __builtin_amdgcn_logf(wghts[m]) - 8.0f * LOG2_2PI - 0.5f * sumlog;
        ((float*)(lds + L_A2))[m] = log2C - 0.5f * LOG2E * qsum;
    }

    // ---- phase C: F staging [x^2(16), x(16)] hi/lo bf16 ----
    {
        int fw = row >> 5, lr = row & 31;     // owning wave region, local row
        float xv[8] = {xa.x, xa.y, xa.z, xa.w, xb.x, xb.y, xb.z, xb.w};
        u16x8 vh2, vl2, vhx, vlx;
#pragma unroll
        for (int d = 0; d < 8; ++d) {
            float q = xv[d] * xv[d];
            unsigned short qh = f2bf(q);
            vh2[d] = qh;               vl2[d] = f2bf(q - bf2f(qh));
            unsigned short xh = f2bf(xv[d]);
            vhx[d] = xh;               vlx[d] = f2bf(xv[d] - bf2f(xh));
        }
        char* fb = lds + L_F + fw * 5120 + lr * 80;
        *(u16x8*)(fb + half * 16)        = vh2;   // k = half*8+d   (x^2 terms)
        *(u16x8*)(fb + 32 + half * 16)   = vhx;   // k = 16+half*8+d (x terms)
        char* fl = fb + 2560;
        *(u16x8*)(fl + half * 16)        = vl2;
        *(u16x8*)(fl + 32 + half * 16)   = vlx;
    }
    __syncthreads();

    // ---- preload B fragments (wave-invariant) ----
    bf16x8 bh[4], bl[4];
    float a2v[4];
#pragma unroll
    for (int c = 0; c < 4; ++c) {
        bh[c] = *(const bf16x8*)(lds + L_WH + (c * 16 + gi) * 80 + gq * 16);
        bl[c] = *(const bf16x8*)(lds + L_WL + (c * 16 + gi) * 80 + gq * 16);
        a2v[c] = ((const float*)(lds + L_A2))[c * 16 + gi];
    }
    bf16x8 mf0 = *(const bf16x8*)(lds + L_MUT + gi * 144 + gq * 16);
    bf16x8 mf1 = *(const bf16x8*)(lds + L_MUT + gi * 144 + 64 + gq * 16);

    const char* fbase = lds + L_F + w * 5120;
    char* pbase = lds + L_P + w * 2304;
    float ll_acc = 0.0f;

#pragma unroll
    for (int rt = 0; rt < 2; ++rt) {
        bf16x8 ah = *(const bf16x8*)(fbase + (rt * 16 + gi) * 80 + gq * 16);
        bf16x8 al = *(const bf16x8*)(fbase + 2560 + (rt * 16 + gi) * 80 + gq * 16);

        // S = fh*wh + fh*wl + fl*wh  (hi/lo split), 4 column tiles of 16 m
        f32x4 pacc[4];
#pragma unroll
        for (int c = 0; c < 4; ++c) {
            f32x4 a = {0.0f, 0.0f, 0.0f, 0.0f};
            a = __builtin_amdgcn_mfma_f32_16x16x32_bf16(al, bh[c], a, 0, 0, 0);
            a = __builtin_amdgcn_mfma_f32_16x16x32_bf16(ah, bl[c], a, 0, 0, 0);
            a = __builtin_amdgcn_mfma_f32_16x16x32_bf16(ah, bh[c], a, 0, 0, 0);
            pacc[c] = a;
        }

        // exp2 + row sums (C layout: row = gq*4+reg, col = c*16+gi)
        float p[4][4], prow[4], inv[4];
#pragma unroll
        for (int reg = 0; reg < 4; ++reg) {
#pragma unroll
            for (int c = 0; c < 4; ++c)
                p[c][reg] = __builtin_amdgcn_exp2f(pacc[c][reg] + a2v[c]);
            prow[reg] = (p[0][reg] + p[1][reg]) + (p[2][reg] + p[3][reg]);
        }
#pragma unroll
        for (int reg = 0; reg < 4; ++reg) {
            float v = prow[reg];
            v += __shfl_xor(v, 1);  v += __shfl_xor(v, 2);
            v += __shfl_xor(v, 4);  v += __shfl_xor(v, 8);
            v = fmaxf(v, 1e-35f);
            ll_acc += __builtin_amdgcn_logf(v);       // log2
            inv[reg] = __builtin_amdgcn_rcpf(v);
        }

        // P -> bf16, C layout -> A layout via wave-local LDS tile
#pragma unroll
        for (int c = 0; c < 4; ++c)
#pragma unroll
            for (int reg = 0; reg < 4; ++reg)
                *(unsigned short*)(pbase + (gq * 4 + reg) * 144 + (c * 16 + gi) * 2) =
                    f2bf(p[c][reg]);

        // E = P @ MU  (K=64, 2 k-steps)
        bf16x8 ap0 = *(const bf16x8*)(pbase + gi * 144 + gq * 16);
        bf16x8 ap1 = *(const bf16x8*)(pbase + gi * 144 + 64 + gq * 16);
        f32x4 e = {0.0f, 0.0f, 0.0f, 0.0f};
        e = __builtin_amdgcn_mfma_f32_16x16x32_bf16(ap0, mf0, e, 0, 0, 0);
        e = __builtin_amdgcn_mfma_f32_16x16x32_bf16(ap1, mf1, e, 0, 0, 0);

        size_t trow = tblk + (size_t)w * 32 + rt * 16 + gq * 4;
#pragma unroll
        for (int reg = 0; reg < 4; ++reg)
            out[1 + (trow + reg) * 16 + gi] = e[reg] * inv[reg];
    }

    // ---- per-block loglike partial (no atomics) ----
    ll_acc += __shfl_xor(ll_acc, 16);
    ll_acc += __shfl_xor(ll_acc, 32);
    if (lane == 0) ((float*)(lds + L_RED))[w] = ll_acc;
    __syncthreads();
    if (tid == 0) {
        float* r = (float*)(lds + L_RED);
        part[blockIdx.x] = (r[0] + r[1]) + (r[2] + r[3]);
    }
}

__global__ void gmm_fin(const float* __restrict__ part, float* __restrict__ out) {
    __shared__ double red[4];
    const int tid = threadIdx.x;
    double s = 0.0;
#pragma unroll
    for (int k = 0; k < 8; ++k) s += (double)part[tid + k * 256];
#pragma unroll
    for (int off = 32; off > 0; off >>= 1) s += __shfl_down(s, off, 64);
    const int wv = tid >> 6, lane = tid & 63;
    if (lane == 0) red[wv] = s;
    __syncthreads();
    if (tid == 0) {
        const double LN2 = 0.6931471805599453;
        double tot = (red[0] + red[1]) + (red[2] + red[3]);
        out[0] = (float)(tot * LN2 / (double)T_TOTAL);
    }
}

extern "C" void kernel_launch(void* const* d_in, const int* in_sizes, int n_in,
                              void* d_out, int out_size, void* d_ws, size_t ws_size,
                              hipStream_t stream) {
    const float* data  = (const float*)d_in[0];
    const float* wghts = (const float*)d_in[1];
    const float* means = (const float*)d_in[2];
    const float* dcovs = (const float*)d_in[3];
    float* out  = (float*)d_out;
    float* part = (float*)d_ws;   // 2048 fp32 partials

    gmm_main<<<T_TOTAL / 128, 256, 0, stream>>>(data, wghts, means, dcovs, out, part);
    gmm_fin<<<1, 256, 0, stream>>>(part, out);
}